// Round 2
// baseline (6286.492 us; speedup 1.0000x reference)
//
#include <hip/hip_runtime.h>
#include <hip/hip_bf16.h>

// GCN classifier: N=100000 nodes, E=1.6M edges, IN=64, HID=128, 64 graphs, 2 classes.
// fp32 throughout (reference is fp32; no fp32 MFMA on CDNA4 -> vector GEMM).
// NOTE: harness passes ALL integer inputs as int32 (not int64).

#define HID 128
#define NGRAPH 64
#define EPSN 1e-5f

// ---------------- degree / counts ----------------
__global__ __launch_bounds__(256) void init_deg(float* deg, int N) {
  int i = blockIdx.x * 256 + threadIdx.x;
  if (i < N) deg[i] = 1.0f;  // self-loop
}

__global__ __launch_bounds__(256) void edge_deg(const int* __restrict__ dst,
                                                float* __restrict__ deg, int E) {
  int e = blockIdx.x * 256 + threadIdx.x;
  if (e < E) atomicAdd(&deg[dst[e]], 1.0f);
}

__global__ __launch_bounds__(256) void deg_to_dis(float* deg, int N) {
  int i = blockIdx.x * 256 + threadIdx.x;
  if (i < N) deg[i] = rsqrtf(deg[i]);
}

__global__ __launch_bounds__(256) void count_nodes(const int* __restrict__ batch,
                                                   float* __restrict__ cnt, int N) {
  int i = blockIdx.x * 256 + threadIdx.x;
  if (i < N) atomicAdd(&cnt[batch[i]], 1.0f);
}

// ---------------- GEMM: Y[N][128] = X[N][K] @ W[K][128] ----------------
// block: 32 nodes x 128 ch; thread: 4 nodes x 4 channels (stride-32 channels).
template <int K>
__global__ __launch_bounds__(256) void gemm_xw(const float* __restrict__ X,
                                               const float* __restrict__ W,
                                               float* __restrict__ Y, int N) {
  __shared__ float Ws[64][HID];
  __shared__ float Xs[32][64];
  const int t = threadIdx.x;
  const int cb = t & 31;   // channel lane
  const int ng = t >> 5;   // node group 0..7
  const int row0 = blockIdx.x * 32;
  float acc[4][4] = {};
  for (int k0 = 0; k0 < K; k0 += 64) {
    for (int i = t; i < 64 * HID / 4; i += 256) {
      ((float4*)&Ws[0][0])[i] = ((const float4*)(W + (size_t)k0 * HID))[i];
    }
    for (int i = t; i < 32 * 64 / 4; i += 256) {
      int r = i >> 4;
      int c4 = i & 15;
      int gr = row0 + r;
      float4 v = make_float4(0.f, 0.f, 0.f, 0.f);
      if (gr < N) v = ((const float4*)(X + (size_t)gr * K + k0))[c4];
      ((float4*)&Xs[r][0])[c4] = v;
    }
    __syncthreads();
#pragma unroll 8
    for (int kk = 0; kk < 64; ++kk) {
      float xv[4], wv[4];
#pragma unroll
      for (int r = 0; r < 4; ++r) xv[r] = Xs[ng * 4 + r][kk];
#pragma unroll
      for (int j = 0; j < 4; ++j) wv[j] = Ws[kk][cb + 32 * j];
#pragma unroll
      for (int r = 0; r < 4; ++r)
#pragma unroll
        for (int j = 0; j < 4; ++j) acc[r][j] += xv[r] * wv[j];
    }
    __syncthreads();
  }
#pragma unroll
  for (int r = 0; r < 4; ++r) {
    int gr = row0 + ng * 4 + r;
    if (gr < N) {
#pragma unroll
      for (int j = 0; j < 4; ++j) Y[(size_t)gr * HID + cb + 32 * j] = acc[r][j];
    }
  }
}

// ---------------- edge scatter: out[dst] += h[src] * dis[src]*dis[dst] ----------------
// 32 threads per edge, 4 consecutive floats each (float4 gather, 4 atomics).
__global__ __launch_bounds__(256) void scatter_edges(const float* __restrict__ H,
                                                     const int* __restrict__ src,
                                                     const int* __restrict__ dst,
                                                     const float* __restrict__ dis,
                                                     float* __restrict__ out, int E) {
  long long gid = (long long)blockIdx.x * 256 + threadIdx.x;
  int e = (int)(gid >> 5);
  if (e >= E) return;
  int lane = (int)(gid & 31);
  int s = src[e];
  int d = dst[e];
  float w = dis[s] * dis[d];
  float4 v = ((const float4*)(H + (size_t)s * HID))[lane];
  float* o = out + (size_t)d * HID + lane * 4;
  atomicAdd(o + 0, v.x * w);
  atomicAdd(o + 1, v.y * w);
  atomicAdd(o + 2, v.z * w);
  atomicAdd(o + 3, v.w * w);
}

// ---------------- self-loop + bias + per-graph sum/sumsq ----------------
// block covers 64 nodes: thread = (half 0/1) x (channel 0..127), 32 nodes each.
__global__ __launch_bounds__(256) void selfbias_stats(float* __restrict__ G,
                                                      const float* __restrict__ H,
                                                      const float* __restrict__ dis,
                                                      const float* __restrict__ bias,
                                                      const int* __restrict__ batch,
                                                      float* __restrict__ gsum,
                                                      float* __restrict__ gsq, int N) {
  const int c = threadIdx.x & 127;
  const int half = threadIdx.x >> 7;
  const int n0 = blockIdx.x * 64 + half * 32;
  const int n1 = min(n0 + 32, N);
  const float b = bias[c];
  float s = 0.f, sq = 0.f;
  int cur = -1;
  for (int n = n0; n < n1; ++n) {
    int g = batch[n];
    if (g != cur) {
      if (cur >= 0) {
        atomicAdd(&gsum[cur * HID + c], s);
        atomicAdd(&gsq[cur * HID + c], sq);
      }
      cur = g; s = 0.f; sq = 0.f;
    }
    float dn = dis[n];
    size_t idx = (size_t)n * HID + c;
    float val = G[idx] + H[idx] * dn * dn + b;
    G[idx] = val;
    s += val;
    sq += val * val;
  }
  if (cur >= 0) {
    atomicAdd(&gsum[cur * HID + c], s);
    atomicAdd(&gsq[cur * HID + c], sq);
  }
}

__global__ __launch_bounds__(256) void finalize_stats(const float* __restrict__ gsum,
                                                      const float* __restrict__ gsq,
                                                      const float* __restrict__ cnt,
                                                      float* __restrict__ mean,
                                                      float* __restrict__ inv) {
  int i = blockIdx.x * 256 + threadIdx.x;
  if (i >= NGRAPH * HID) return;
  int g = i >> 7;
  float c = fmaxf(cnt[g], 1.f);
  float m = gsum[i] / c;
  float v = gsq[i] / c - m * m;
  mean[i] = m;
  inv[i] = rsqrtf(v + EPSN);
}

__global__ __launch_bounds__(256) void norm_relu(const float* __restrict__ G,
                                                 const int* __restrict__ batch,
                                                 const float* __restrict__ mean,
                                                 const float* __restrict__ inv,
                                                 float* __restrict__ out, int N) {
  size_t i = (size_t)blockIdx.x * 256 + threadIdx.x;
  if (i >= (size_t)N * HID) return;
  int n = (int)(i >> 7);
  int c = (int)(i & 127);
  int g = batch[n];
  float v = (G[i] - mean[g * HID + c]) * inv[g * HID + c];
  out[i] = fmaxf(v, 0.f);
}

// layer-2 tail: normalized relu value accumulated into per-graph pooled sums.
__global__ __launch_bounds__(256) void norm_relu_pool(const float* __restrict__ G,
                                                      const int* __restrict__ batch,
                                                      const float* __restrict__ mean,
                                                      const float* __restrict__ inv,
                                                      float* __restrict__ pooled, int N) {
  const int c = threadIdx.x & 127;
  const int half = threadIdx.x >> 7;
  const int n0 = blockIdx.x * 64 + half * 32;
  const int n1 = min(n0 + 32, N);
  float s = 0.f;
  int cur = -1;
  for (int n = n0; n < n1; ++n) {
    int g = batch[n];
    if (g != cur) {
      if (cur >= 0) atomicAdd(&pooled[cur * HID + c], s);
      cur = g; s = 0.f;
    }
    float v = (G[(size_t)n * HID + c] - mean[g * HID + c]) * inv[g * HID + c];
    s += fmaxf(v, 0.f);
  }
  if (cur >= 0) atomicAdd(&pooled[cur * HID + c], s);
}

// ---------------- final head: pooled mean -> batchnorm over graphs -> FC ----------------
__global__ __launch_bounds__(256) void final_head(const float* __restrict__ pooled_sum,
                                                  const float* __restrict__ cnt,
                                                  const float* __restrict__ gamma,
                                                  const float* __restrict__ beta,
                                                  const float* __restrict__ fcW,
                                                  const float* __restrict__ fcb,
                                                  float* __restrict__ out) {
  __shared__ float P[NGRAPH][HID];
  __shared__ float zs[HID], zb[HID];
  int t = threadIdx.x;
  for (int i = t; i < NGRAPH * HID; i += 256) {
    int g = i >> 7;
    P[g][i & 127] = pooled_sum[i] / fmaxf(cnt[g], 1.f);
  }
  __syncthreads();
  if (t < HID) {
    float m = 0.f;
    for (int g = 0; g < NGRAPH; ++g) m += P[g][t];
    m *= (1.f / NGRAPH);
    float v = 0.f;
    for (int g = 0; g < NGRAPH; ++g) {
      float d = P[g][t] - m;
      v += d * d;
    }
    v *= (1.f / NGRAPH);
    float sc = rsqrtf(v + EPSN) * gamma[t];
    zs[t] = sc;
    zb[t] = beta[t] - m * sc;
  }
  __syncthreads();
  if (t < NGRAPH * 2) {
    int g = t >> 1, k = t & 1;
    float acc = fcb[k];
    for (int c = 0; c < HID; ++c) {
      float z = P[g][c] * zs[c] + zb[c];
      acc += z * fcW[c * 2 + k];
    }
    out[t] = acc;
  }
}

extern "C" void kernel_launch(void* const* d_in, const int* in_sizes, int n_in,
                              void* d_out, int out_size, void* d_ws, size_t ws_size,
                              hipStream_t stream) {
  const float* x = (const float*)d_in[0];
  const int* ei = (const int*)d_in[1];      // int32 (harness converts int64 -> int32)
  const int* batch = (const int*)d_in[2];   // int32
  const float* W1 = (const float*)d_in[3];
  const float* b1 = (const float*)d_in[4];
  const float* W2 = (const float*)d_in[5];
  const float* b2 = (const float*)d_in[6];
  const float* gamma = (const float*)d_in[7];
  const float* beta = (const float*)d_in[8];
  const float* fcW = (const float*)d_in[9];
  const float* fcb = (const float*)d_in[10];
  float* out = (float*)d_out;

  const int N = in_sizes[2];
  const int E = in_sizes[1] / 2;
  const int* srcp = ei;
  const int* dstp = ei + E;

  // workspace layout (floats); total ~103 MB
  float* ws = (float*)d_ws;
  size_t off = 0;
  auto alloc = [&](size_t n) {
    float* p = ws + off;
    off += (n + 127) & ~(size_t)127;
    return p;
  };
  float* dis = alloc(N);                    // deg -> dis (in place)
  float* A = alloc((size_t)N * HID);        // h (transformed)
  float* B = alloc((size_t)N * HID);        // aggregated
  float* stats0 = ws + off;                 // start of small stats region
  float* gsum1 = alloc(NGRAPH * HID);
  float* gsq1 = alloc(NGRAPH * HID);
  float* gsum2 = alloc(NGRAPH * HID);
  float* gsq2 = alloc(NGRAPH * HID);
  float* mean1 = alloc(NGRAPH * HID);
  float* inv1 = alloc(NGRAPH * HID);
  float* mean2 = alloc(NGRAPH * HID);
  float* inv2 = alloc(NGRAPH * HID);
  float* cnt = alloc(NGRAPH);
  float* pooled = alloc(NGRAPH * HID);
  size_t stats_bytes = (size_t)((ws + off) - stats0) * sizeof(float);

  const int nblkN = (N + 255) / 256;
  const int nblkE = (E + 255) / 256;

  // zero accumulators
  hipMemsetAsync(stats0, 0, stats_bytes, stream);
  hipMemsetAsync(B, 0, (size_t)N * HID * sizeof(float), stream);

  // degree / counts
  init_deg<<<nblkN, 256, 0, stream>>>(dis, N);
  edge_deg<<<nblkE, 256, 0, stream>>>(dstp, dis, E);
  count_nodes<<<nblkN, 256, 0, stream>>>(batch, cnt, N);
  deg_to_dis<<<nblkN, 256, 0, stream>>>(dis, N);

  // ---- layer 1 ----
  gemm_xw<64><<<(N + 31) / 32, 256, 0, stream>>>(x, W1, A, N);
  {
    long long total = (long long)E * 32;
    int blocks = (int)((total + 255) / 256);
    scatter_edges<<<blocks, 256, 0, stream>>>(A, srcp, dstp, dis, B, E);
  }
  selfbias_stats<<<(N + 63) / 64, 256, 0, stream>>>(B, A, dis, b1, batch, gsum1, gsq1, N);
  finalize_stats<<<(NGRAPH * HID + 255) / 256, 256, 0, stream>>>(gsum1, gsq1, cnt, mean1, inv1);
  {
    long long total = (long long)N * HID;
    int blocks = (int)((total + 255) / 256);
    norm_relu<<<blocks, 256, 0, stream>>>(B, batch, mean1, inv1, A, N);
  }

  // ---- layer 2 ----
  gemm_xw<128><<<(N + 31) / 32, 256, 0, stream>>>(A, W2, B, N);
  hipMemsetAsync(A, 0, (size_t)N * HID * sizeof(float), stream);
  {
    long long total = (long long)E * 32;
    int blocks = (int)((total + 255) / 256);
    scatter_edges<<<blocks, 256, 0, stream>>>(B, srcp, dstp, dis, A, E);
  }
  selfbias_stats<<<(N + 63) / 64, 256, 0, stream>>>(A, B, dis, b2, batch, gsum2, gsq2, N);
  finalize_stats<<<(NGRAPH * HID + 255) / 256, 256, 0, stream>>>(gsum2, gsq2, cnt, mean2, inv2);
  norm_relu_pool<<<(N + 63) / 64, 256, 0, stream>>>(A, batch, mean2, inv2, pooled, N);

  // ---- head ----
  final_head<<<1, 256, 0, stream>>>(pooled, cnt, gamma, beta, fcW, fcb, out);
}

// Round 3
// 1285.129 us; speedup vs baseline: 4.8917x; 4.8917x over previous
//
#include <hip/hip_runtime.h>
#include <hip/hip_bf16.h>

// GCN classifier: N=100000 nodes, E=1.6M edges, IN=64, HID=128, 64 graphs, 2 classes.
// Round 2: replace edge-scatter atomics (3.2GB HBM writes, 2.7ms each) with
// per-call CSR build + gather-based aggregation (one wave per node).

#define HID 128
#define NGRAPH 64
#define EPSN 1e-5f

// ---------------- degree / counts ----------------
__global__ __launch_bounds__(256) void count_in(const int* __restrict__ dst,
                                                int* __restrict__ counts, int E) {
  int e = blockIdx.x * 256 + threadIdx.x;
  if (e < E) atomicAdd(&counts[dst[e]], 1);
}

__global__ __launch_bounds__(256) void dis_from_counts(const int* __restrict__ counts,
                                                       float* __restrict__ dis, int N) {
  int i = blockIdx.x * 256 + threadIdx.x;
  if (i < N) dis[i] = rsqrtf((float)counts[i] + 1.0f);  // +1 self-loop
}

__global__ __launch_bounds__(256) void count_nodes(const int* __restrict__ batch,
                                                   float* __restrict__ cnt, int N) {
  int i = blockIdx.x * 256 + threadIdx.x;
  if (i < N) atomicAdd(&cnt[batch[i]], 1.0f);
}

// ---------------- prefix scan (counts -> row_ptr, cursor) ----------------
__global__ __launch_bounds__(256) void scan_pass1(const int* __restrict__ counts,
                                                  int* __restrict__ bsum, int N) {
  int i = blockIdx.x * 256 + threadIdx.x;
  int v = (i < N) ? counts[i] : 0;
#pragma unroll
  for (int o = 32; o > 0; o >>= 1) v += __shfl_down(v, o, 64);
  __shared__ int ws[4];
  if ((threadIdx.x & 63) == 0) ws[threadIdx.x >> 6] = v;
  __syncthreads();
  if (threadIdx.x == 0) bsum[blockIdx.x] = ws[0] + ws[1] + ws[2] + ws[3];
}

__global__ __launch_bounds__(512) void scan_pass2(int* __restrict__ bsum, int nb) {
  __shared__ int sm[512];
  int t = threadIdx.x;
  int v = (t < nb) ? bsum[t] : 0;
  sm[t] = v;
  __syncthreads();
  for (int off = 1; off < 512; off <<= 1) {
    int add = (t >= off) ? sm[t - off] : 0;
    __syncthreads();
    sm[t] += add;
    __syncthreads();
  }
  if (t < nb) bsum[t] = sm[t] - v;  // exclusive
}

// writes row_ptr[i] and reuses counts[] as cursor[]
__global__ __launch_bounds__(256) void scan_pass3(int* __restrict__ counts,
                                                  const int* __restrict__ bsum,
                                                  int* __restrict__ row_ptr, int N, int E) {
  __shared__ int sm[256];
  int t = threadIdx.x;
  int i = blockIdx.x * 256 + t;
  int v = (i < N) ? counts[i] : 0;
  sm[t] = v;
  __syncthreads();
  for (int off = 1; off < 256; off <<= 1) {
    int add = (t >= off) ? sm[t - off] : 0;
    __syncthreads();
    sm[t] += add;
    __syncthreads();
  }
  int excl = sm[t] - v + bsum[blockIdx.x];
  if (i < N) {
    row_ptr[i] = excl;
    counts[i] = excl;  // cursor
  }
  if (i == 0) row_ptr[N] = E;
}

__global__ __launch_bounds__(256) void fill_csr(const int* __restrict__ src,
                                                const int* __restrict__ dst,
                                                int* __restrict__ cursor,
                                                int* __restrict__ esrc, int E) {
  int e = blockIdx.x * 256 + threadIdx.x;
  if (e < E) {
    int pos = atomicAdd(&cursor[dst[e]], 1);
    esrc[pos] = src[e];
  }
}

// ---------------- GEMM: Y[N][128] = X[N][K] @ W[K][128] ----------------
template <int K>
__global__ __launch_bounds__(256) void gemm_xw(const float* __restrict__ X,
                                               const float* __restrict__ W,
                                               float* __restrict__ Y, int N) {
  __shared__ float Ws[64][HID];
  __shared__ float Xs[32][64];
  const int t = threadIdx.x;
  const int cb = t & 31;
  const int ng = t >> 5;
  const int row0 = blockIdx.x * 32;
  float acc[4][4] = {};
  for (int k0 = 0; k0 < K; k0 += 64) {
    for (int i = t; i < 64 * HID / 4; i += 256) {
      ((float4*)&Ws[0][0])[i] = ((const float4*)(W + (size_t)k0 * HID))[i];
    }
    for (int i = t; i < 32 * 64 / 4; i += 256) {
      int r = i >> 4;
      int c4 = i & 15;
      int gr = row0 + r;
      float4 v = make_float4(0.f, 0.f, 0.f, 0.f);
      if (gr < N) v = ((const float4*)(X + (size_t)gr * K + k0))[c4];
      ((float4*)&Xs[r][0])[c4] = v;
    }
    __syncthreads();
#pragma unroll 8
    for (int kk = 0; kk < 64; ++kk) {
      float xv[4], wv[4];
#pragma unroll
      for (int r = 0; r < 4; ++r) xv[r] = Xs[ng * 4 + r][kk];
#pragma unroll
      for (int j = 0; j < 4; ++j) wv[j] = Ws[kk][cb + 32 * j];
#pragma unroll
      for (int r = 0; r < 4; ++r)
#pragma unroll
        for (int j = 0; j < 4; ++j) acc[r][j] += xv[r] * wv[j];
    }
    __syncthreads();
  }
#pragma unroll
  for (int r = 0; r < 4; ++r) {
    int gr = row0 + ng * 4 + r;
    if (gr < N) {
#pragma unroll
      for (int j = 0; j < 4; ++j) Y[(size_t)gr * HID + cb + 32 * j] = acc[r][j];
    }
  }
}

// ---------------- gather aggregation: one wave per node ----------------
// out[n] = sum_{e: dst=n} H[src]*dis[src]*dis[n] + H[n]*dis[n]^2 + bias
__global__ __launch_bounds__(256) void aggregate(const float* __restrict__ H,
                                                 const int* __restrict__ row_ptr,
                                                 const int* __restrict__ esrc,
                                                 const float* __restrict__ dis,
                                                 const float* __restrict__ bias,
                                                 float* __restrict__ out, int N) {
  int wid = (int)((blockIdx.x * 256 + threadIdx.x) >> 6);
  if (wid >= N) return;
  const int lane = threadIdx.x & 63;
  const int n = wid;
  const float dn = dis[n];
  const int beg = row_ptr[n];
  const int end = row_ptr[n + 1];
  float ax = 0.f, ay = 0.f;
  int e = beg;
  for (; e + 1 < end; e += 2) {
    int s0 = esrc[e];
    int s1 = esrc[e + 1];
    float w0 = dis[s0] * dn;
    float w1 = dis[s1] * dn;
    float2 v0 = ((const float2*)(H + (size_t)s0 * HID))[lane];
    float2 v1 = ((const float2*)(H + (size_t)s1 * HID))[lane];
    ax += v0.x * w0 + v1.x * w1;
    ay += v0.y * w0 + v1.y * w1;
  }
  if (e < end) {
    int s0 = esrc[e];
    float w0 = dis[s0] * dn;
    float2 v0 = ((const float2*)(H + (size_t)s0 * HID))[lane];
    ax += v0.x * w0;
    ay += v0.y * w0;
  }
  float2 hv = ((const float2*)(H + (size_t)n * HID))[lane];
  float2 b = ((const float2*)bias)[lane];
  float wself = dn * dn;
  float2 r;
  r.x = ax + hv.x * wself + b.x;
  r.y = ay + hv.y * wself + b.y;
  ((float2*)(out + (size_t)n * HID))[lane] = r;
}

// ---------------- per-graph sum/sumsq (streaming, segment-batched atomics) ----------------
__global__ __launch_bounds__(256) void stats_pass(const float* __restrict__ G,
                                                  const int* __restrict__ batch,
                                                  float* __restrict__ gsum,
                                                  float* __restrict__ gsq, int N) {
  const int c = threadIdx.x & 127;
  const int half = threadIdx.x >> 7;
  const int n0 = blockIdx.x * 64 + half * 32;
  const int n1 = min(n0 + 32, N);
  float s = 0.f, sq = 0.f;
  int cur = -1;
  for (int n = n0; n < n1; ++n) {
    int g = batch[n];
    if (g != cur) {
      if (cur >= 0) {
        atomicAdd(&gsum[cur * HID + c], s);
        atomicAdd(&gsq[cur * HID + c], sq);
      }
      cur = g; s = 0.f; sq = 0.f;
    }
    float val = G[(size_t)n * HID + c];
    s += val;
    sq += val * val;
  }
  if (cur >= 0) {
    atomicAdd(&gsum[cur * HID + c], s);
    atomicAdd(&gsq[cur * HID + c], sq);
  }
}

__global__ __launch_bounds__(256) void finalize_stats(const float* __restrict__ gsum,
                                                      const float* __restrict__ gsq,
                                                      const float* __restrict__ cnt,
                                                      float* __restrict__ mean,
                                                      float* __restrict__ inv) {
  int i = blockIdx.x * 256 + threadIdx.x;
  if (i >= NGRAPH * HID) return;
  int g = i >> 7;
  float c = fmaxf(cnt[g], 1.f);
  float m = gsum[i] / c;
  float v = gsq[i] / c - m * m;
  mean[i] = m;
  inv[i] = rsqrtf(v + EPSN);
}

__global__ __launch_bounds__(256) void norm_relu(const float* __restrict__ G,
                                                 const int* __restrict__ batch,
                                                 const float* __restrict__ mean,
                                                 const float* __restrict__ inv,
                                                 float* __restrict__ out, int N) {
  size_t i = (size_t)blockIdx.x * 256 + threadIdx.x;
  if (i >= (size_t)N * HID) return;
  int n = (int)(i >> 7);
  int c = (int)(i & 127);
  int g = batch[n];
  float v = (G[i] - mean[g * HID + c]) * inv[g * HID + c];
  out[i] = fmaxf(v, 0.f);
}

__global__ __launch_bounds__(256) void norm_relu_pool(const float* __restrict__ G,
                                                      const int* __restrict__ batch,
                                                      const float* __restrict__ mean,
                                                      const float* __restrict__ inv,
                                                      float* __restrict__ pooled, int N) {
  const int c = threadIdx.x & 127;
  const int half = threadIdx.x >> 7;
  const int n0 = blockIdx.x * 64 + half * 32;
  const int n1 = min(n0 + 32, N);
  float s = 0.f;
  int cur = -1;
  for (int n = n0; n < n1; ++n) {
    int g = batch[n];
    if (g != cur) {
      if (cur >= 0) atomicAdd(&pooled[cur * HID + c], s);
      cur = g; s = 0.f;
    }
    float v = (G[(size_t)n * HID + c] - mean[g * HID + c]) * inv[g * HID + c];
    s += fmaxf(v, 0.f);
  }
  if (cur >= 0) atomicAdd(&pooled[cur * HID + c], s);
}

// ---------------- final head ----------------
__global__ __launch_bounds__(256) void final_head(const float* __restrict__ pooled_sum,
                                                  const float* __restrict__ cnt,
                                                  const float* __restrict__ gamma,
                                                  const float* __restrict__ beta,
                                                  const float* __restrict__ fcW,
                                                  const float* __restrict__ fcb,
                                                  float* __restrict__ out) {
  __shared__ float P[NGRAPH][HID];
  __shared__ float zs[HID], zb[HID];
  int t = threadIdx.x;
  for (int i = t; i < NGRAPH * HID; i += 256) {
    int g = i >> 7;
    P[g][i & 127] = pooled_sum[i] / fmaxf(cnt[g], 1.f);
  }
  __syncthreads();
  if (t < HID) {
    float m = 0.f;
    for (int g = 0; g < NGRAPH; ++g) m += P[g][t];
    m *= (1.f / NGRAPH);
    float v = 0.f;
    for (int g = 0; g < NGRAPH; ++g) {
      float d = P[g][t] - m;
      v += d * d;
    }
    v *= (1.f / NGRAPH);
    float sc = rsqrtf(v + EPSN) * gamma[t];
    zs[t] = sc;
    zb[t] = beta[t] - m * sc;
  }
  __syncthreads();
  if (t < NGRAPH * 2) {
    int g = t >> 1, k = t & 1;
    float acc = fcb[k];
    for (int c = 0; c < HID; ++c) {
      float z = P[g][c] * zs[c] + zb[c];
      acc += z * fcW[c * 2 + k];
    }
    out[t] = acc;
  }
}

extern "C" void kernel_launch(void* const* d_in, const int* in_sizes, int n_in,
                              void* d_out, int out_size, void* d_ws, size_t ws_size,
                              hipStream_t stream) {
  const float* x = (const float*)d_in[0];
  const int* ei = (const int*)d_in[1];      // int32
  const int* batch = (const int*)d_in[2];   // int32
  const float* W1 = (const float*)d_in[3];
  const float* b1 = (const float*)d_in[4];
  const float* W2 = (const float*)d_in[5];
  const float* b2 = (const float*)d_in[6];
  const float* gamma = (const float*)d_in[7];
  const float* beta = (const float*)d_in[8];
  const float* fcW = (const float*)d_in[9];
  const float* fcb = (const float*)d_in[10];
  float* out = (float*)d_out;

  const int N = in_sizes[2];
  const int E = in_sizes[1] / 2;
  const int* srcp = ei;
  const int* dstp = ei + E;

  // workspace layout
  float* ws = (float*)d_ws;
  size_t off = 0;
  auto alloc = [&](size_t n) {
    float* p = ws + off;
    off += (n + 127) & ~(size_t)127;
    return p;
  };
  int* counts = (int*)alloc(N);          // counts -> cursor (reused)
  int* row_ptr = (int*)alloc(N + 1);
  int* esrc = (int*)alloc(E);
  int* bsum = (int*)alloc(1024);
  float* dis = alloc(N);
  float* A = alloc((size_t)N * HID);
  float* B = alloc((size_t)N * HID);
  float* zero0 = ws + off;               // start of zeroed stats region
  float* gsum1 = alloc(NGRAPH * HID);
  float* gsq1 = alloc(NGRAPH * HID);
  float* gsum2 = alloc(NGRAPH * HID);
  float* gsq2 = alloc(NGRAPH * HID);
  float* pooled = alloc(NGRAPH * HID);
  float* cnt = alloc(NGRAPH);
  size_t zero_bytes = (size_t)((ws + off) - zero0) * sizeof(float);
  float* mean1 = alloc(NGRAPH * HID);
  float* inv1 = alloc(NGRAPH * HID);
  float* mean2 = alloc(NGRAPH * HID);
  float* inv2 = alloc(NGRAPH * HID);

  const int nblkN = (N + 255) / 256;
  const int nblkE = (E + 255) / 256;
  const int NB = nblkN;  // scan blocks (<=512 for N<=131072)

  hipMemsetAsync(counts, 0, (size_t)N * sizeof(int), stream);
  hipMemsetAsync(zero0, 0, zero_bytes, stream);

  // degree, counts, CSR
  count_in<<<nblkE, 256, 0, stream>>>(dstp, counts, E);
  count_nodes<<<nblkN, 256, 0, stream>>>(batch, cnt, N);
  dis_from_counts<<<nblkN, 256, 0, stream>>>(counts, dis, N);
  scan_pass1<<<NB, 256, 0, stream>>>(counts, bsum, N);
  scan_pass2<<<1, 512, 0, stream>>>(bsum, NB);
  scan_pass3<<<NB, 256, 0, stream>>>(counts, bsum, row_ptr, N, E);
  fill_csr<<<nblkE, 256, 0, stream>>>(srcp, dstp, counts, esrc, E);

  const int aggBlocks = (N + 3) / 4;  // one wave per node, 4 waves/block

  // ---- layer 1 ----
  gemm_xw<64><<<(N + 31) / 32, 256, 0, stream>>>(x, W1, A, N);
  aggregate<<<aggBlocks, 256, 0, stream>>>(A, row_ptr, esrc, dis, b1, B, N);
  stats_pass<<<(N + 63) / 64, 256, 0, stream>>>(B, batch, gsum1, gsq1, N);
  finalize_stats<<<(NGRAPH * HID + 255) / 256, 256, 0, stream>>>(gsum1, gsq1, cnt, mean1, inv1);
  {
    long long total = (long long)N * HID;
    int blocks = (int)((total + 255) / 256);
    norm_relu<<<blocks, 256, 0, stream>>>(B, batch, mean1, inv1, A, N);
  }

  // ---- layer 2 ----
  gemm_xw<128><<<(N + 31) / 32, 256, 0, stream>>>(A, W2, B, N);
  aggregate<<<aggBlocks, 256, 0, stream>>>(B, row_ptr, esrc, dis, b2, A, N);
  stats_pass<<<(N + 63) / 64, 256, 0, stream>>>(A, batch, gsum2, gsq2, N);
  finalize_stats<<<(NGRAPH * HID + 255) / 256, 256, 0, stream>>>(gsum2, gsq2, cnt, mean2, inv2);
  norm_relu_pool<<<(N + 63) / 64, 256, 0, stream>>>(A, batch, mean2, inv2, pooled, N);

  // ---- head ----
  final_head<<<1, 256, 0, stream>>>(pooled, cnt, gamma, beta, fcW, fcb, out);
}

// Round 4
// 647.754 us; speedup vs baseline: 9.7051x; 1.9840x over previous
//
#include <hip/hip_runtime.h>
#include <hip/hip_bf16.h>

// GCN classifier: N=100000 nodes, E=1.6M edges, IN=64, HID=128, 64 graphs, 2 classes.
// Round 3: batch[] is SORTED -> per-graph counts via boundary detection, no
// 100K-to-64-address atomic contention (was 632us/dispatch, half the runtime).

#define HID 128
#define NGRAPH 64
#define EPSN 1e-5f

// ---------------- degree ----------------
__global__ __launch_bounds__(256) void count_in(const int* __restrict__ dst,
                                                int* __restrict__ counts, int E) {
  int e = blockIdx.x * 256 + threadIdx.x;
  if (e < E) atomicAdd(&counts[dst[e]], 1);
}

__global__ __launch_bounds__(256) void dis_from_counts(const int* __restrict__ counts,
                                                       float* __restrict__ dis, int N) {
  int i = blockIdx.x * 256 + threadIdx.x;
  if (i < N) dis[i] = rsqrtf((float)counts[i] + 1.0f);  // +1 self-loop
}

// ---------------- per-graph segment boundaries (batch sorted) ----------------
__global__ __launch_bounds__(256) void graph_starts(const int* __restrict__ batch,
                                                    int* __restrict__ gstart, int N) {
  int i = blockIdx.x * 256 + threadIdx.x;
  if (i >= N) return;
  int g = batch[i];
  if (i == 0) {
    for (int q = 0; q <= g; ++q) gstart[q] = 0;
  } else {
    int gp = batch[i - 1];
    if (g != gp)
      for (int q = gp + 1; q <= g; ++q) gstart[q] = i;
  }
  if (i == N - 1)
    for (int q = g + 1; q <= NGRAPH; ++q) gstart[q] = N;
}

__global__ __launch_bounds__(64) void cnt_from_starts(const int* __restrict__ gstart,
                                                      float* __restrict__ cnt) {
  int g = threadIdx.x;
  if (g < NGRAPH) cnt[g] = (float)(gstart[g + 1] - gstart[g]);
}

// ---------------- prefix scan (counts -> row_ptr, cursor) ----------------
__global__ __launch_bounds__(256) void scan_pass1(const int* __restrict__ counts,
                                                  int* __restrict__ bsum, int N) {
  int i = blockIdx.x * 256 + threadIdx.x;
  int v = (i < N) ? counts[i] : 0;
#pragma unroll
  for (int o = 32; o > 0; o >>= 1) v += __shfl_down(v, o, 64);
  __shared__ int ws[4];
  if ((threadIdx.x & 63) == 0) ws[threadIdx.x >> 6] = v;
  __syncthreads();
  if (threadIdx.x == 0) bsum[blockIdx.x] = ws[0] + ws[1] + ws[2] + ws[3];
}

__global__ __launch_bounds__(512) void scan_pass2(int* __restrict__ bsum, int nb) {
  __shared__ int sm[512];
  int t = threadIdx.x;
  int v = (t < nb) ? bsum[t] : 0;
  sm[t] = v;
  __syncthreads();
  for (int off = 1; off < 512; off <<= 1) {
    int add = (t >= off) ? sm[t - off] : 0;
    __syncthreads();
    sm[t] += add;
    __syncthreads();
  }
  if (t < nb) bsum[t] = sm[t] - v;  // exclusive
}

__global__ __launch_bounds__(256) void scan_pass3(int* __restrict__ counts,
                                                  const int* __restrict__ bsum,
                                                  int* __restrict__ row_ptr, int N, int E) {
  __shared__ int sm[256];
  int t = threadIdx.x;
  int i = blockIdx.x * 256 + t;
  int v = (i < N) ? counts[i] : 0;
  sm[t] = v;
  __syncthreads();
  for (int off = 1; off < 256; off <<= 1) {
    int add = (t >= off) ? sm[t - off] : 0;
    __syncthreads();
    sm[t] += add;
    __syncthreads();
  }
  int excl = sm[t] - v + bsum[blockIdx.x];
  if (i < N) {
    row_ptr[i] = excl;
    counts[i] = excl;  // cursor
  }
  if (i == 0) row_ptr[N] = E;
}

__global__ __launch_bounds__(256) void fill_csr(const int* __restrict__ src,
                                                const int* __restrict__ dst,
                                                int* __restrict__ cursor,
                                                int* __restrict__ esrc, int E) {
  int e = blockIdx.x * 256 + threadIdx.x;
  if (e < E) {
    int pos = atomicAdd(&cursor[dst[e]], 1);
    esrc[pos] = src[e];
  }
}

// ---------------- GEMM: Y[N][128] = X[N][K] @ W[K][128] ----------------
template <int K>
__global__ __launch_bounds__(256) void gemm_xw(const float* __restrict__ X,
                                               const float* __restrict__ W,
                                               float* __restrict__ Y, int N) {
  __shared__ float Ws[64][HID];
  __shared__ float Xs[32][64];
  const int t = threadIdx.x;
  const int cb = t & 31;
  const int ng = t >> 5;
  const int row0 = blockIdx.x * 32;
  float acc[4][4] = {};
  for (int k0 = 0; k0 < K; k0 += 64) {
    for (int i = t; i < 64 * HID / 4; i += 256) {
      ((float4*)&Ws[0][0])[i] = ((const float4*)(W + (size_t)k0 * HID))[i];
    }
    for (int i = t; i < 32 * 64 / 4; i += 256) {
      int r = i >> 4;
      int c4 = i & 15;
      int gr = row0 + r;
      float4 v = make_float4(0.f, 0.f, 0.f, 0.f);
      if (gr < N) v = ((const float4*)(X + (size_t)gr * K + k0))[c4];
      ((float4*)&Xs[r][0])[c4] = v;
    }
    __syncthreads();
#pragma unroll 8
    for (int kk = 0; kk < 64; ++kk) {
      float xv[4], wv[4];
#pragma unroll
      for (int r = 0; r < 4; ++r) xv[r] = Xs[ng * 4 + r][kk];
#pragma unroll
      for (int j = 0; j < 4; ++j) wv[j] = Ws[kk][cb + 32 * j];
#pragma unroll
      for (int r = 0; r < 4; ++r)
#pragma unroll
        for (int j = 0; j < 4; ++j) acc[r][j] += xv[r] * wv[j];
    }
    __syncthreads();
  }
#pragma unroll
  for (int r = 0; r < 4; ++r) {
    int gr = row0 + ng * 4 + r;
    if (gr < N) {
#pragma unroll
      for (int j = 0; j < 4; ++j) Y[(size_t)gr * HID + cb + 32 * j] = acc[r][j];
    }
  }
}

// ---------------- gather aggregation: one wave per node ----------------
__global__ __launch_bounds__(256) void aggregate(const float* __restrict__ H,
                                                 const int* __restrict__ row_ptr,
                                                 const int* __restrict__ esrc,
                                                 const float* __restrict__ dis,
                                                 const float* __restrict__ bias,
                                                 float* __restrict__ out, int N) {
  int wid = (int)((blockIdx.x * 256 + threadIdx.x) >> 6);
  if (wid >= N) return;
  const int lane = threadIdx.x & 63;
  const int n = wid;
  const float dn = dis[n];
  const int beg = row_ptr[n];
  const int end = row_ptr[n + 1];
  float ax = 0.f, ay = 0.f;
  int e = beg;
  for (; e + 1 < end; e += 2) {
    int s0 = esrc[e];
    int s1 = esrc[e + 1];
    float w0 = dis[s0] * dn;
    float w1 = dis[s1] * dn;
    float2 v0 = ((const float2*)(H + (size_t)s0 * HID))[lane];
    float2 v1 = ((const float2*)(H + (size_t)s1 * HID))[lane];
    ax += v0.x * w0 + v1.x * w1;
    ay += v0.y * w0 + v1.y * w1;
  }
  if (e < end) {
    int s0 = esrc[e];
    float w0 = dis[s0] * dn;
    float2 v0 = ((const float2*)(H + (size_t)s0 * HID))[lane];
    ax += v0.x * w0;
    ay += v0.y * w0;
  }
  float2 hv = ((const float2*)(H + (size_t)n * HID))[lane];
  float2 b = ((const float2*)bias)[lane];
  float wself = dn * dn;
  float2 r;
  r.x = ax + hv.x * wself + b.x;
  r.y = ay + hv.y * wself + b.y;
  ((float2*)(out + (size_t)n * HID))[lane] = r;
}

// ---------------- per-graph sum/sumsq ----------------
__global__ __launch_bounds__(256) void stats_pass(const float* __restrict__ G,
                                                  const int* __restrict__ batch,
                                                  float* __restrict__ gsum,
                                                  float* __restrict__ gsq, int N) {
  const int c = threadIdx.x & 127;
  const int half = threadIdx.x >> 7;
  const int n0 = blockIdx.x * 64 + half * 32;
  const int n1 = min(n0 + 32, N);
  float s = 0.f, sq = 0.f;
  int cur = -1;
  for (int n = n0; n < n1; ++n) {
    int g = batch[n];
    if (g != cur) {
      if (cur >= 0) {
        atomicAdd(&gsum[cur * HID + c], s);
        atomicAdd(&gsq[cur * HID + c], sq);
      }
      cur = g; s = 0.f; sq = 0.f;
    }
    float val = G[(size_t)n * HID + c];
    s += val;
    sq += val * val;
  }
  if (cur >= 0) {
    atomicAdd(&gsum[cur * HID + c], s);
    atomicAdd(&gsq[cur * HID + c], sq);
  }
}

__global__ __launch_bounds__(256) void finalize_stats(const float* __restrict__ gsum,
                                                      const float* __restrict__ gsq,
                                                      const float* __restrict__ cnt,
                                                      float* __restrict__ mean,
                                                      float* __restrict__ inv) {
  int i = blockIdx.x * 256 + threadIdx.x;
  if (i >= NGRAPH * HID) return;
  int g = i >> 7;
  float c = fmaxf(cnt[g], 1.f);
  float m = gsum[i] / c;
  float v = gsq[i] / c - m * m;
  mean[i] = m;
  inv[i] = rsqrtf(v + EPSN);
}

__global__ __launch_bounds__(256) void norm_relu(const float* __restrict__ G,
                                                 const int* __restrict__ batch,
                                                 const float* __restrict__ mean,
                                                 const float* __restrict__ inv,
                                                 float* __restrict__ out, int N) {
  size_t i = (size_t)blockIdx.x * 256 + threadIdx.x;
  if (i >= (size_t)N * HID) return;
  int n = (int)(i >> 7);
  int c = (int)(i & 127);
  int g = batch[n];
  float v = (G[i] - mean[g * HID + c]) * inv[g * HID + c];
  out[i] = fmaxf(v, 0.f);
}

__global__ __launch_bounds__(256) void norm_relu_pool(const float* __restrict__ G,
                                                      const int* __restrict__ batch,
                                                      const float* __restrict__ mean,
                                                      const float* __restrict__ inv,
                                                      float* __restrict__ pooled, int N) {
  const int c = threadIdx.x & 127;
  const int half = threadIdx.x >> 7;
  const int n0 = blockIdx.x * 64 + half * 32;
  const int n1 = min(n0 + 32, N);
  float s = 0.f;
  int cur = -1;
  for (int n = n0; n < n1; ++n) {
    int g = batch[n];
    if (g != cur) {
      if (cur >= 0) atomicAdd(&pooled[cur * HID + c], s);
      cur = g; s = 0.f;
    }
    float v = (G[(size_t)n * HID + c] - mean[g * HID + c]) * inv[g * HID + c];
    s += fmaxf(v, 0.f);
  }
  if (cur >= 0) atomicAdd(&pooled[cur * HID + c], s);
}

// ---------------- final head ----------------
__global__ __launch_bounds__(256) void final_head(const float* __restrict__ pooled_sum,
                                                  const float* __restrict__ cnt,
                                                  const float* __restrict__ gamma,
                                                  const float* __restrict__ beta,
                                                  const float* __restrict__ fcW,
                                                  const float* __restrict__ fcb,
                                                  float* __restrict__ out) {
  __shared__ float P[NGRAPH][HID];
  __shared__ float zs[HID], zb[HID];
  int t = threadIdx.x;
  for (int i = t; i < NGRAPH * HID; i += 256) {
    int g = i >> 7;
    P[g][i & 127] = pooled_sum[i] / fmaxf(cnt[g], 1.f);
  }
  __syncthreads();
  if (t < HID) {
    float m = 0.f;
    for (int g = 0; g < NGRAPH; ++g) m += P[g][t];
    m *= (1.f / NGRAPH);
    float v = 0.f;
    for (int g = 0; g < NGRAPH; ++g) {
      float d = P[g][t] - m;
      v += d * d;
    }
    v *= (1.f / NGRAPH);
    float sc = rsqrtf(v + EPSN) * gamma[t];
    zs[t] = sc;
    zb[t] = beta[t] - m * sc;
  }
  __syncthreads();
  if (t < NGRAPH * 2) {
    int g = t >> 1, k = t & 1;
    float acc = fcb[k];
    for (int c = 0; c < HID; ++c) {
      float z = P[g][c] * zs[c] + zb[c];
      acc += z * fcW[c * 2 + k];
    }
    out[t] = acc;
  }
}

extern "C" void kernel_launch(void* const* d_in, const int* in_sizes, int n_in,
                              void* d_out, int out_size, void* d_ws, size_t ws_size,
                              hipStream_t stream) {
  const float* x = (const float*)d_in[0];
  const int* ei = (const int*)d_in[1];      // int32
  const int* batch = (const int*)d_in[2];   // int32 (sorted)
  const float* W1 = (const float*)d_in[3];
  const float* b1 = (const float*)d_in[4];
  const float* W2 = (const float*)d_in[5];
  const float* b2 = (const float*)d_in[6];
  const float* gamma = (const float*)d_in[7];
  const float* beta = (const float*)d_in[8];
  const float* fcW = (const float*)d_in[9];
  const float* fcb = (const float*)d_in[10];
  float* out = (float*)d_out;

  const int N = in_sizes[2];
  const int E = in_sizes[1] / 2;
  const int* srcp = ei;
  const int* dstp = ei + E;

  // workspace layout
  float* ws = (float*)d_ws;
  size_t off = 0;
  auto alloc = [&](size_t n) {
    float* p = ws + off;
    off += (n + 127) & ~(size_t)127;
    return p;
  };
  int* counts = (int*)alloc(N);          // counts -> cursor (reused)
  int* row_ptr = (int*)alloc(N + 1);
  int* esrc = (int*)alloc(E);
  int* bsum = (int*)alloc(1024);
  int* gstart = (int*)alloc(NGRAPH + 1);
  float* dis = alloc(N);
  float* A = alloc((size_t)N * HID);
  float* B = alloc((size_t)N * HID);
  float* zero0 = ws + off;               // start of zeroed stats region
  float* gsum1 = alloc(NGRAPH * HID);
  float* gsq1 = alloc(NGRAPH * HID);
  float* gsum2 = alloc(NGRAPH * HID);
  float* gsq2 = alloc(NGRAPH * HID);
  float* pooled = alloc(NGRAPH * HID);
  size_t zero_bytes = (size_t)((ws + off) - zero0) * sizeof(float);
  float* cnt = alloc(NGRAPH);
  float* mean1 = alloc(NGRAPH * HID);
  float* inv1 = alloc(NGRAPH * HID);
  float* mean2 = alloc(NGRAPH * HID);
  float* inv2 = alloc(NGRAPH * HID);

  const int nblkN = (N + 255) / 256;
  const int nblkE = (E + 255) / 256;
  const int NB = nblkN;  // scan blocks (<=512 for N<=131072)

  hipMemsetAsync(counts, 0, (size_t)N * sizeof(int), stream);
  hipMemsetAsync(zero0, 0, zero_bytes, stream);

  // degree, per-graph segments, CSR
  count_in<<<nblkE, 256, 0, stream>>>(dstp, counts, E);
  graph_starts<<<nblkN, 256, 0, stream>>>(batch, gstart, N);
  cnt_from_starts<<<1, 64, 0, stream>>>(gstart, cnt);
  dis_from_counts<<<nblkN, 256, 0, stream>>>(counts, dis, N);
  scan_pass1<<<NB, 256, 0, stream>>>(counts, bsum, N);
  scan_pass2<<<1, 512, 0, stream>>>(bsum, NB);
  scan_pass3<<<NB, 256, 0, stream>>>(counts, bsum, row_ptr, N, E);
  fill_csr<<<nblkE, 256, 0, stream>>>(srcp, dstp, counts, esrc, E);

  const int aggBlocks = (N + 3) / 4;  // one wave per node, 4 waves/block

  // ---- layer 1 ----
  gemm_xw<64><<<(N + 31) / 32, 256, 0, stream>>>(x, W1, A, N);
  aggregate<<<aggBlocks, 256, 0, stream>>>(A, row_ptr, esrc, dis, b1, B, N);
  stats_pass<<<(N + 63) / 64, 256, 0, stream>>>(B, batch, gsum1, gsq1, N);
  finalize_stats<<<(NGRAPH * HID + 255) / 256, 256, 0, stream>>>(gsum1, gsq1, cnt, mean1, inv1);
  {
    long long total = (long long)N * HID;
    int blocks = (int)((total + 255) / 256);
    norm_relu<<<blocks, 256, 0, stream>>>(B, batch, mean1, inv1, A, N);
  }

  // ---- layer 2 ----
  gemm_xw<128><<<(N + 31) / 32, 256, 0, stream>>>(A, W2, B, N);
  aggregate<<<aggBlocks, 256, 0, stream>>>(B, row_ptr, esrc, dis, b2, A, N);
  stats_pass<<<(N + 63) / 64, 256, 0, stream>>>(A, batch, gsum2, gsq2, N);
  finalize_stats<<<(NGRAPH * HID + 255) / 256, 256, 0, stream>>>(gsum2, gsq2, cnt, mean2, inv2);
  norm_relu_pool<<<(N + 63) / 64, 256, 0, stream>>>(A, batch, mean2, inv2, pooled, N);

  // ---- head ----
  final_head<<<1, 256, 0, stream>>>(pooled, cnt, gamma, beta, fcW, fcb, out);
}

// Round 5
// 580.135 us; speedup vs baseline: 10.8363x; 1.1166x over previous
//
#include <hip/hip_runtime.h>
#include <hip/hip_bf16.h>

// GCN classifier: N=100000, E=1.6M, IN=64, HID=128, 64 graphs, 2 classes.
// Round 4: (Ax)W1 re-association (half layer-1 gather), bf16 h2 gather (half
// layer-2 gather), norm+relu fused into GEMM2 staging, float4-LDS GEMM tiles.

#define HID 128
#define NGRAPH 64
#define EPSN 1e-5f

typedef unsigned int uint;
typedef unsigned short ushort;

static __device__ __forceinline__ ushort f2bf(float f) {  // round-nearest-even
  uint x = __float_as_uint(f);
  return (ushort)((x + 0x7FFFu + ((x >> 16) & 1u)) >> 16);
}

// ---------------- degree ----------------
__global__ __launch_bounds__(256) void count_in(const int* __restrict__ dst,
                                                int* __restrict__ counts, int E) {
  int e = blockIdx.x * 256 + threadIdx.x;
  if (e < E) atomicAdd(&counts[dst[e]], 1);
}

__global__ __launch_bounds__(256) void dis_from_counts(const int* __restrict__ counts,
                                                       float* __restrict__ dis, int N) {
  int i = blockIdx.x * 256 + threadIdx.x;
  if (i < N) dis[i] = rsqrtf((float)counts[i] + 1.0f);  // +1 self-loop
}

// ---------------- per-graph segment boundaries (batch sorted) ----------------
__global__ __launch_bounds__(256) void graph_starts(const int* __restrict__ batch,
                                                    int* __restrict__ gstart, int N) {
  int i = blockIdx.x * 256 + threadIdx.x;
  if (i >= N) return;
  int g = batch[i];
  if (i == 0) {
    for (int q = 0; q <= g; ++q) gstart[q] = 0;
  } else {
    int gp = batch[i - 1];
    if (g != gp)
      for (int q = gp + 1; q <= g; ++q) gstart[q] = i;
  }
  if (i == N - 1)
    for (int q = g + 1; q <= NGRAPH; ++q) gstart[q] = N;
}

__global__ __launch_bounds__(64) void cnt_from_starts(const int* __restrict__ gstart,
                                                      float* __restrict__ cnt) {
  int g = threadIdx.x;
  if (g < NGRAPH) cnt[g] = (float)(gstart[g + 1] - gstart[g]);
}

// ---------------- prefix scan (counts -> row_ptr, cursor) ----------------
__global__ __launch_bounds__(256) void scan_pass1(const int* __restrict__ counts,
                                                  int* __restrict__ bsum, int N) {
  int i = blockIdx.x * 256 + threadIdx.x;
  int v = (i < N) ? counts[i] : 0;
#pragma unroll
  for (int o = 32; o > 0; o >>= 1) v += __shfl_down(v, o, 64);
  __shared__ int ws[4];
  if ((threadIdx.x & 63) == 0) ws[threadIdx.x >> 6] = v;
  __syncthreads();
  if (threadIdx.x == 0) bsum[blockIdx.x] = ws[0] + ws[1] + ws[2] + ws[3];
}

__global__ __launch_bounds__(512) void scan_pass2(int* __restrict__ bsum, int nb) {
  __shared__ int sm[512];
  int t = threadIdx.x;
  int v = (t < nb) ? bsum[t] : 0;
  sm[t] = v;
  __syncthreads();
  for (int off = 1; off < 512; off <<= 1) {
    int add = (t >= off) ? sm[t - off] : 0;
    __syncthreads();
    sm[t] += add;
    __syncthreads();
  }
  if (t < nb) bsum[t] = sm[t] - v;  // exclusive
}

__global__ __launch_bounds__(256) void scan_pass3(int* __restrict__ counts,
                                                  const int* __restrict__ bsum,
                                                  int* __restrict__ row_ptr, int N, int E) {
  __shared__ int sm[256];
  int t = threadIdx.x;
  int i = blockIdx.x * 256 + t;
  int v = (i < N) ? counts[i] : 0;
  sm[t] = v;
  __syncthreads();
  for (int off = 1; off < 256; off <<= 1) {
    int add = (t >= off) ? sm[t - off] : 0;
    __syncthreads();
    sm[t] += add;
    __syncthreads();
  }
  int excl = sm[t] - v + bsum[blockIdx.x];
  if (i < N) {
    row_ptr[i] = excl;
    counts[i] = excl;  // cursor
  }
  if (i == 0) row_ptr[N] = E;
}

__global__ __launch_bounds__(256) void fill_csr(const int* __restrict__ src,
                                                const int* __restrict__ dst,
                                                int* __restrict__ cursor,
                                                int* __restrict__ esrc, int E) {
  int e = blockIdx.x * 256 + threadIdx.x;
  if (e < E) {
    int pos = atomicAdd(&cursor[dst[e]], 1);
    esrc[pos] = src[e];
  }
}

// ---------------- aggregate 64-ch fp32: y = A x (one wave per node) ----------------
__global__ __launch_bounds__(256) void aggregate64(const float* __restrict__ X,
                                                   const int* __restrict__ row_ptr,
                                                   const int* __restrict__ esrc,
                                                   const float* __restrict__ dis,
                                                   float* __restrict__ out, int N) {
  int wid = (int)((blockIdx.x * 256 + threadIdx.x) >> 6);
  if (wid >= N) return;
  const int lane = threadIdx.x & 63;
  const float dn = dis[wid];
  const int beg = row_ptr[wid];
  const int end = row_ptr[wid + 1];
  float a = 0.f;
  int e = beg;
  for (; e + 1 < end; e += 2) {
    int s0 = esrc[e];
    int s1 = esrc[e + 1];
    float w0 = dis[s0];
    float w1 = dis[s1];
    a += X[(size_t)s0 * 64 + lane] * w0 + X[(size_t)s1 * 64 + lane] * w1;
  }
  if (e < end) {
    int s0 = esrc[e];
    a += X[(size_t)s0 * 64 + lane] * dis[s0];
  }
  a *= dn;  // dis[dst] factored out of the edge sum
  a += X[(size_t)wid * 64 + lane] * dn * dn;  // self-loop
  out[(size_t)wid * 64 + lane] = a;
}

// ---------------- aggregate 128-ch bf16 + bias: z = A h2 + b (fp32 out) ----------------
__global__ __launch_bounds__(256) void aggregate128_bf16(const ushort* __restrict__ H,
                                                         const int* __restrict__ row_ptr,
                                                         const int* __restrict__ esrc,
                                                         const float* __restrict__ dis,
                                                         const float* __restrict__ bias,
                                                         float* __restrict__ out, int N) {
  int wid = (int)((blockIdx.x * 256 + threadIdx.x) >> 6);
  if (wid >= N) return;
  const int lane = threadIdx.x & 63;
  const float dn = dis[wid];
  const int beg = row_ptr[wid];
  const int end = row_ptr[wid + 1];
  float ax = 0.f, ay = 0.f;
  int e = beg;
  for (; e + 1 < end; e += 2) {
    int s0 = esrc[e];
    int s1 = esrc[e + 1];
    float w0 = dis[s0];
    float w1 = dis[s1];
    uint u0 = *(const uint*)(H + (size_t)s0 * HID + 2 * lane);
    uint u1 = *(const uint*)(H + (size_t)s1 * HID + 2 * lane);
    ax += __uint_as_float(u0 << 16) * w0 + __uint_as_float(u1 << 16) * w1;
    ay += __uint_as_float(u0 & 0xFFFF0000u) * w0 + __uint_as_float(u1 & 0xFFFF0000u) * w1;
  }
  if (e < end) {
    int s0 = esrc[e];
    float w0 = dis[s0];
    uint u0 = *(const uint*)(H + (size_t)s0 * HID + 2 * lane);
    ax += __uint_as_float(u0 << 16) * w0;
    ay += __uint_as_float(u0 & 0xFFFF0000u) * w0;
  }
  ax *= dn;
  ay *= dn;
  uint us = *(const uint*)(H + (size_t)wid * HID + 2 * lane);
  float wself = dn * dn;
  ax += __uint_as_float(us << 16) * wself;
  ay += __uint_as_float(us & 0xFFFF0000u) * wself;
  float2 b = ((const float2*)bias)[lane];
  float2 r;
  r.x = ax + b.x;
  r.y = ay + b.y;
  ((float2*)(out + (size_t)wid * HID))[lane] = r;
}

// ---------------- GEMM tile: Y[N][128] = X[N][K] @ W[K][128] (+bias) ----------------
// 64 rows x 128 ch per block, 256 threads; thread = 4 rows x 8 contiguous ch.
// FUSE_NORM: apply instance-norm + relu to X during staging.
// OUT_BF16: store output rounded to bf16 (for the bf16 gather).
template <int K, bool FUSE_NORM, bool OUT_BF16>
__global__ __launch_bounds__(256) void gemm_tile(const float* __restrict__ X,
                                                 const float* __restrict__ W,
                                                 const float* __restrict__ bias,
                                                 const int* __restrict__ batch,
                                                 const float* __restrict__ mean,
                                                 const float* __restrict__ inv,
                                                 float* __restrict__ Yf,
                                                 ushort* __restrict__ Yh, int N) {
  __shared__ float Xs[64][68];   // pad 68: float4-aligned rows (272B), spread banks
  __shared__ float Ws[64][HID];
  const int t = threadIdx.x;
  const int r0 = (t >> 4) * 4;
  const int c0 = (t & 15) * 8;
  const int row0 = blockIdx.x * 64;
  float acc[4][8] = {};
  for (int k0 = 0; k0 < K; k0 += 64) {
    for (int i = t; i < 64 * 32; i += 256) {  // W: 64x128 in float4 units
      int kk = i >> 5;
      int c4 = i & 31;
      ((float4*)&Ws[kk][0])[c4] = ((const float4*)(W + (size_t)(k0 + kk) * HID))[c4];
    }
    for (int i = t; i < 64 * 16; i += 256) {  // X: 64 rows x 64 k in float4 units
      int r = i >> 4;
      int c4 = i & 15;
      int gr = row0 + r;
      float4 v = make_float4(0.f, 0.f, 0.f, 0.f);
      if (gr < N) {
        v = ((const float4*)(X + (size_t)gr * K + k0))[c4];
        if (FUSE_NORM) {
          int g = batch[gr];
          const float* mp = mean + g * HID + k0 + c4 * 4;
          const float* ip = inv + g * HID + k0 + c4 * 4;
          v.x = fmaxf((v.x - mp[0]) * ip[0], 0.f);
          v.y = fmaxf((v.y - mp[1]) * ip[1], 0.f);
          v.z = fmaxf((v.z - mp[2]) * ip[2], 0.f);
          v.w = fmaxf((v.w - mp[3]) * ip[3], 0.f);
        }
      }
      *(float4*)&Xs[r][c4 * 4] = v;
    }
    __syncthreads();
#pragma unroll 4
    for (int kk = 0; kk < 64; ++kk) {
      float4 w0 = *(const float4*)&Ws[kk][c0];
      float4 w1 = *(const float4*)&Ws[kk][c0 + 4];
      float xr[4];
#pragma unroll
      for (int i = 0; i < 4; ++i) xr[i] = Xs[r0 + i][kk];
#pragma unroll
      for (int i = 0; i < 4; ++i) {
        acc[i][0] += xr[i] * w0.x;
        acc[i][1] += xr[i] * w0.y;
        acc[i][2] += xr[i] * w0.z;
        acc[i][3] += xr[i] * w0.w;
        acc[i][4] += xr[i] * w1.x;
        acc[i][5] += xr[i] * w1.y;
        acc[i][6] += xr[i] * w1.z;
        acc[i][7] += xr[i] * w1.w;
      }
    }
    __syncthreads();
  }
  float bv[8];
#pragma unroll
  for (int j = 0; j < 8; ++j) bv[j] = bias ? bias[c0 + j] : 0.f;
#pragma unroll
  for (int i = 0; i < 4; ++i) {
    int gr = row0 + r0 + i;
    if (gr < N) {
      if (OUT_BF16) {
        uint4 u;
        u.x = (uint)f2bf(acc[i][0] + bv[0]) | ((uint)f2bf(acc[i][1] + bv[1]) << 16);
        u.y = (uint)f2bf(acc[i][2] + bv[2]) | ((uint)f2bf(acc[i][3] + bv[3]) << 16);
        u.z = (uint)f2bf(acc[i][4] + bv[4]) | ((uint)f2bf(acc[i][5] + bv[5]) << 16);
        u.w = (uint)f2bf(acc[i][6] + bv[6]) | ((uint)f2bf(acc[i][7] + bv[7]) << 16);
        *(uint4*)(Yh + (size_t)gr * HID + c0) = u;
      } else {
        float4 o0 = make_float4(acc[i][0] + bv[0], acc[i][1] + bv[1], acc[i][2] + bv[2],
                                acc[i][3] + bv[3]);
        float4 o1 = make_float4(acc[i][4] + bv[4], acc[i][5] + bv[5], acc[i][6] + bv[6],
                                acc[i][7] + bv[7]);
        *(float4*)(Yf + (size_t)gr * HID + c0) = o0;
        *(float4*)(Yf + (size_t)gr * HID + c0 + 4) = o1;
      }
    }
  }
}

// ---------------- per-graph sum/sumsq ----------------
__global__ __launch_bounds__(256) void stats_pass(const float* __restrict__ G,
                                                  const int* __restrict__ batch,
                                                  float* __restrict__ gsum,
                                                  float* __restrict__ gsq, int N) {
  const int c = threadIdx.x & 127;
  const int half = threadIdx.x >> 7;
  const int n0 = blockIdx.x * 64 + half * 32;
  const int n1 = min(n0 + 32, N);
  float s = 0.f, sq = 0.f;
  int cur = -1;
  for (int n = n0; n < n1; ++n) {
    int g = batch[n];
    if (g != cur) {
      if (cur >= 0) {
        atomicAdd(&gsum[cur * HID + c], s);
        atomicAdd(&gsq[cur * HID + c], sq);
      }
      cur = g;
      s = 0.f;
      sq = 0.f;
    }
    float val = G[(size_t)n * HID + c];
    s += val;
    sq += val * val;
  }
  if (cur >= 0) {
    atomicAdd(&gsum[cur * HID + c], s);
    atomicAdd(&gsq[cur * HID + c], sq);
  }
}

__global__ __launch_bounds__(256) void finalize_stats(const float* __restrict__ gsum,
                                                      const float* __restrict__ gsq,
                                                      const float* __restrict__ cnt,
                                                      float* __restrict__ mean,
                                                      float* __restrict__ inv) {
  int i = blockIdx.x * 256 + threadIdx.x;
  if (i >= NGRAPH * HID) return;
  int g = i >> 7;
  float c = fmaxf(cnt[g], 1.f);
  float m = gsum[i] / c;
  float v = gsq[i] / c - m * m;
  mean[i] = m;
  inv[i] = rsqrtf(v + EPSN);
}

__global__ __launch_bounds__(256) void norm_relu_pool(const float* __restrict__ G,
                                                      const int* __restrict__ batch,
                                                      const float* __restrict__ mean,
                                                      const float* __restrict__ inv,
                                                      float* __restrict__ pooled, int N) {
  const int c = threadIdx.x & 127;
  const int half = threadIdx.x >> 7;
  const int n0 = blockIdx.x * 64 + half * 32;
  const int n1 = min(n0 + 32, N);
  float s = 0.f;
  int cur = -1;
  for (int n = n0; n < n1; ++n) {
    int g = batch[n];
    if (g != cur) {
      if (cur >= 0) atomicAdd(&pooled[cur * HID + c], s);
      cur = g;
      s = 0.f;
    }
    float v = (G[(size_t)n * HID + c] - mean[g * HID + c]) * inv[g * HID + c];
    s += fmaxf(v, 0.f);
  }
  if (cur >= 0) atomicAdd(&pooled[cur * HID + c], s);
}

// ---------------- final head ----------------
__global__ __launch_bounds__(256) void final_head(const float* __restrict__ pooled_sum,
                                                  const float* __restrict__ cnt,
                                                  const float* __restrict__ gamma,
                                                  const float* __restrict__ beta,
                                                  const float* __restrict__ fcW,
                                                  const float* __restrict__ fcb,
                                                  float* __restrict__ out) {
  __shared__ float P[NGRAPH][HID];
  __shared__ float zs[HID], zb[HID];
  int t = threadIdx.x;
  for (int i = t; i < NGRAPH * HID; i += 256) {
    int g = i >> 7;
    P[g][i & 127] = pooled_sum[i] / fmaxf(cnt[g], 1.f);
  }
  __syncthreads();
  if (t < HID) {
    float m = 0.f;
    for (int g = 0; g < NGRAPH; ++g) m += P[g][t];
    m *= (1.f / NGRAPH);
    float v = 0.f;
    for (int g = 0; g < NGRAPH; ++g) {
      float d = P[g][t] - m;
      v += d * d;
    }
    v *= (1.f / NGRAPH);
    float sc = rsqrtf(v + EPSN) * gamma[t];
    zs[t] = sc;
    zb[t] = beta[t] - m * sc;
  }
  __syncthreads();
  if (t < NGRAPH * 2) {
    int g = t >> 1, k = t & 1;
    float acc = fcb[k];
    for (int c = 0; c < HID; ++c) {
      float z = P[g][c] * zs[c] + zb[c];
      acc += z * fcW[c * 2 + k];
    }
    out[t] = acc;
  }
}

extern "C" void kernel_launch(void* const* d_in, const int* in_sizes, int n_in,
                              void* d_out, int out_size, void* d_ws, size_t ws_size,
                              hipStream_t stream) {
  const float* x = (const float*)d_in[0];
  const int* ei = (const int*)d_in[1];     // int32
  const int* batch = (const int*)d_in[2];  // int32 (sorted)
  const float* W1 = (const float*)d_in[3];
  const float* b1 = (const float*)d_in[4];
  const float* W2 = (const float*)d_in[5];
  const float* b2 = (const float*)d_in[6];
  const float* gamma = (const float*)d_in[7];
  const float* beta = (const float*)d_in[8];
  const float* fcW = (const float*)d_in[9];
  const float* fcb = (const float*)d_in[10];
  float* out = (float*)d_out;

  const int N = in_sizes[2];
  const int E = in_sizes[1] / 2;
  const int* srcp = ei;
  const int* dstp = ei + E;

  // workspace layout (floats)
  float* ws = (float*)d_ws;
  size_t off = 0;
  auto alloc = [&](size_t n) {
    float* p = ws + off;
    off += (n + 127) & ~(size_t)127;
    return p;
  };
  int* counts = (int*)alloc(N);       // counts -> cursor (reused)
  int* row_ptr = (int*)alloc(N + 1);
  int* esrc = (int*)alloc(E);
  int* bsum = (int*)alloc(1024);
  int* gstart = (int*)alloc(NGRAPH + 1);
  float* dis = alloc(N);
  float* y1 = alloc((size_t)N * 64);   // 25.6MB: y1 (f32 Nx64) then h2 (bf16 Nx128)
  float* h1p = alloc((size_t)N * HID); // 51.2MB: h1' (gemm1 out) then z (agg2 out)
  float* zero0 = ws + off;             // zeroed stats region
  float* gsum1 = alloc(NGRAPH * HID);
  float* gsq1 = alloc(NGRAPH * HID);
  float* gsum2 = alloc(NGRAPH * HID);
  float* gsq2 = alloc(NGRAPH * HID);
  float* pooled = alloc(NGRAPH * HID);
  size_t zero_bytes = (size_t)((ws + off) - zero0) * sizeof(float);
  float* cnt = alloc(NGRAPH);
  float* mean1 = alloc(NGRAPH * HID);
  float* inv1 = alloc(NGRAPH * HID);
  float* mean2 = alloc(NGRAPH * HID);
  float* inv2 = alloc(NGRAPH * HID);
  ushort* h2 = (ushort*)y1;

  const int nblkN = (N + 255) / 256;
  const int nblkE = (E + 255) / 256;
  const int NB = nblkN;

  hipMemsetAsync(counts, 0, (size_t)N * sizeof(int), stream);
  hipMemsetAsync(zero0, 0, zero_bytes, stream);

  // degree, segments, CSR
  count_in<<<nblkE, 256, 0, stream>>>(dstp, counts, E);
  graph_starts<<<nblkN, 256, 0, stream>>>(batch, gstart, N);
  cnt_from_starts<<<1, 64, 0, stream>>>(gstart, cnt);
  dis_from_counts<<<nblkN, 256, 0, stream>>>(counts, dis, N);
  scan_pass1<<<NB, 256, 0, stream>>>(counts, bsum, N);
  scan_pass2<<<1, 512, 0, stream>>>(bsum, NB);
  scan_pass3<<<NB, 256, 0, stream>>>(counts, bsum, row_ptr, N, E);
  fill_csr<<<nblkE, 256, 0, stream>>>(srcp, dstp, counts, esrc, E);

  const int aggBlocks = (N + 3) / 4;      // one wave per node
  const int gemmBlocks = (N + 63) / 64;   // 64 rows per block

  // ---- layer 1: y1 = A x ; h1' = y1 @ W1 + b1 ----
  aggregate64<<<aggBlocks, 256, 0, stream>>>(x, row_ptr, esrc, dis, y1, N);
  gemm_tile<64, false, false><<<gemmBlocks, 256, 0, stream>>>(
      y1, W1, b1, nullptr, nullptr, nullptr, h1p, nullptr, N);
  stats_pass<<<(N + 63) / 64, 256, 0, stream>>>(h1p, batch, gsum1, gsq1, N);
  finalize_stats<<<(NGRAPH * HID + 255) / 256, 256, 0, stream>>>(gsum1, gsq1, cnt, mean1, inv1);

  // ---- layer 2: h2 = relu(norm(h1')) @ W2 (bf16) ; z = A h2 + b2 ----
  gemm_tile<128, true, true><<<gemmBlocks, 256, 0, stream>>>(
      h1p, W2, nullptr, batch, mean1, inv1, nullptr, h2, N);
  aggregate128_bf16<<<aggBlocks, 256, 0, stream>>>(h2, row_ptr, esrc, dis, b2, h1p, N);
  stats_pass<<<(N + 63) / 64, 256, 0, stream>>>(h1p, batch, gsum2, gsq2, N);
  finalize_stats<<<(NGRAPH * HID + 255) / 256, 256, 0, stream>>>(gsum2, gsq2, cnt, mean2, inv2);
  norm_relu_pool<<<(N + 63) / 64, 256, 0, stream>>>(h1p, batch, mean2, inv2, pooled, N);

  // ---- head ----
  final_head<<<1, 256, 0, stream>>>(pooled, cnt, gamma, beta, fcW, fcb, out);
}

// Round 6
// 429.625 us; speedup vs baseline: 14.6325x; 1.3503x over previous
//
#include <hip/hip_runtime.h>
#include <hip/hip_bf16.h>

// GCN classifier: N=100000, E=1.6M, IN=64, HID=128, 64 graphs, 2 classes.
// Round 5: bucketed counting-sort CSR build (single-writer lines, kills the
// 16x write amplification of fill_csr), bf16 dis-prescaled gathers both layers.

#define HID 128
#define NGRAPH 64
#define EPSN 1e-5f
#define BSHIFT 8            // 256 nodes per bucket
#define NBMAX 512

typedef unsigned int uint;
typedef unsigned short ushort;

static __device__ __forceinline__ ushort f2bf(float f) {  // round-nearest-even
  uint x = __float_as_uint(f);
  return (ushort)((x + 0x7FFFu + ((x >> 16) & 1u)) >> 16);
}
static __device__ __forceinline__ float bf2f(ushort u) {
  return __uint_as_float((uint)u << 16);
}

// ---------------- per-graph segment boundaries (batch sorted) ----------------
__global__ __launch_bounds__(256) void graph_starts(const int* __restrict__ batch,
                                                    int* __restrict__ gstart, int N) {
  int i = blockIdx.x * 256 + threadIdx.x;
  if (i >= N) return;
  int g = batch[i];
  if (i == 0) {
    for (int q = 0; q <= g; ++q) gstart[q] = 0;
  } else {
    int gp = batch[i - 1];
    if (g != gp)
      for (int q = gp + 1; q <= g; ++q) gstart[q] = i;
  }
  if (i == N - 1)
    for (int q = g + 1; q <= NGRAPH; ++q) gstart[q] = N;
}

__global__ __launch_bounds__(64) void cnt_from_starts(const int* __restrict__ gstart,
                                                      float* __restrict__ cnt) {
  int g = threadIdx.x;
  if (g < NGRAPH) cnt[g] = (float)(gstart[g + 1] - gstart[g]);
}

// ---------------- bucketed counting sort: CSR build ----------------
// 1) per-block LDS histogram of dst>>8 -> global bucket counts
__global__ __launch_bounds__(256) void bucket_count(const int* __restrict__ dst,
                                                    int* __restrict__ bcnt, int E, int NB) {
  __shared__ int h[NBMAX];
  for (int i = threadIdx.x; i < NB; i += 256) h[i] = 0;
  __syncthreads();
  int e0 = blockIdx.x * 4096;
#pragma unroll
  for (int k = 0; k < 16; ++k) {
    int e = e0 + k * 256 + threadIdx.x;
    if (e < E) atomicAdd(&h[dst[e] >> BSHIFT], 1);
  }
  __syncthreads();
  for (int i = threadIdx.x; i < NB; i += 256)
    if (h[i]) atomicAdd(&bcnt[i], h[i]);
}

// 2) exclusive scan of bucket counts (NB <= 512)
__global__ __launch_bounds__(512) void bucket_scan(const int* __restrict__ bcnt,
                                                   int* __restrict__ bbase,
                                                   int* __restrict__ bcursor, int NB, int E) {
  __shared__ int sm[512];
  int t = threadIdx.x;
  int v = (t < NB) ? bcnt[t] : 0;
  sm[t] = v;
  __syncthreads();
  for (int off = 1; off < 512; off <<= 1) {
    int add = (t >= off) ? sm[t - off] : 0;
    __syncthreads();
    sm[t] += add;
    __syncthreads();
  }
  if (t < NB) {
    int excl = sm[t] - v;
    bbase[t] = excl;
    bcursor[t] = excl;
  }
  if (t == 0) bbase[NB] = E;
}

// 3) bin edges into bucket regions; each block claims contiguous per-bucket
//    ranges (one atomic per block x bucket) -> dense, mostly single-writer lines.
__global__ __launch_bounds__(256) void bin_edges(const int* __restrict__ src,
                                                 const int* __restrict__ dst,
                                                 int* __restrict__ bcursor,
                                                 int2* __restrict__ records, int E, int NB) {
  __shared__ int h[NBMAX];
  __shared__ int base[NBMAX];
  for (int i = threadIdx.x; i < NB; i += 256) h[i] = 0;
  __syncthreads();
  int e0 = blockIdx.x * 4096;
  int d[16], s[16];
#pragma unroll
  for (int k = 0; k < 16; ++k) {
    int e = e0 + k * 256 + threadIdx.x;
    if (e < E) {
      d[k] = dst[e];
      s[k] = src[e];
      atomicAdd(&h[d[k] >> BSHIFT], 1);
    }
  }
  __syncthreads();
  for (int i = threadIdx.x; i < NB; i += 256) {
    int c = h[i];
    if (c) base[i] = atomicAdd(&bcursor[i], c);
  }
  __syncthreads();
  for (int i = threadIdx.x; i < NB; i += 256) h[i] = 0;  // reuse as local cursor
  __syncthreads();
#pragma unroll
  for (int k = 0; k < 16; ++k) {
    int e = e0 + k * 256 + threadIdx.x;
    if (e < E) {
      int b = d[k] >> BSHIFT;
      int lp = atomicAdd(&h[b], 1);
      records[base[b] + lp] = make_int2(s[k], d[k]);
    }
  }
}

// 4) one block per bucket: local count/scan -> row_ptr, dis, esrc (coalesced,
//    single-writer 12.5KB region per block -> ~1x write amplification).
__global__ __launch_bounds__(256) void build_csr(const int2* __restrict__ records,
                                                 const int* __restrict__ bbase,
                                                 int* __restrict__ row_ptr,
                                                 float* __restrict__ dis,
                                                 int* __restrict__ esrc, int N, int E) {
  const int b = blockIdx.x;
  const int node0 = b << BSHIFT;
  const int nn = min(256, N - node0);
  const int beg = bbase[b];
  const int cnt = bbase[b + 1] - beg;
  const int t = threadIdx.x;
  __shared__ int lc[256], sc[256], lcur[256];
  lc[t] = 0;
  __syncthreads();
  for (int i = t; i < cnt; i += 256) atomicAdd(&lc[records[beg + i].y - node0], 1);
  __syncthreads();
  int myc = lc[t];
  sc[t] = myc;
  __syncthreads();
  for (int off = 1; off < 256; off <<= 1) {
    int add = (t >= off) ? sc[t - off] : 0;
    __syncthreads();
    sc[t] += add;
    __syncthreads();
  }
  int excl = sc[t] - myc;
  if (t < nn) {
    row_ptr[node0 + t] = beg + excl;
    dis[node0 + t] = rsqrtf((float)myc + 1.0f);  // +1 self-loop
  }
  lcur[t] = excl;
  __syncthreads();
  for (int i = t; i < cnt; i += 256) {
    int2 r = records[beg + i];
    int p = atomicAdd(&lcur[r.y - node0], 1);
    esrc[beg + p] = r.x;
  }
  if (b == 0 && t == 0) row_ptr[N] = E;
}

// ---------------- xs = bf16(x * dis[row])  (prescale bakes edge weight) ----------------
__global__ __launch_bounds__(256) void xscale_bf16(const float* __restrict__ X,
                                                   const float* __restrict__ dis,
                                                   ushort* __restrict__ XS, int n4) {
  int i4 = blockIdx.x * 256 + threadIdx.x;  // unit = float4
  if (i4 >= n4) return;
  int n = i4 >> 4;  // 16 float4 per 64-ch row
  float dn = dis[n];
  float4 v = ((const float4*)X)[i4];
  ushort4 u;
  u.x = f2bf(v.x * dn);
  u.y = f2bf(v.y * dn);
  u.z = f2bf(v.z * dn);
  u.w = f2bf(v.w * dn);
  ((ushort4*)XS)[i4] = u;
}

// ---------------- aggregate 64-ch bf16 (prescaled): y = dn*(sum_e xs[s] + xs[n]) ----------------
__global__ __launch_bounds__(256) void aggregate64_bf16(const ushort* __restrict__ XS,
                                                        const int* __restrict__ row_ptr,
                                                        const int* __restrict__ esrc,
                                                        const float* __restrict__ dis,
                                                        float* __restrict__ out, int N) {
  int wid = (int)((blockIdx.x * 256 + threadIdx.x) >> 6);
  if (wid >= N) return;
  const int lane = threadIdx.x & 63;
  const float dn = dis[wid];
  const int beg = row_ptr[wid];
  const int end = row_ptr[wid + 1];
  float a = 0.f;
  int e = beg;
  for (; e + 1 < end; e += 2) {
    int s0 = esrc[e], s1 = esrc[e + 1];
    a += bf2f(XS[(size_t)s0 * 64 + lane]) + bf2f(XS[(size_t)s1 * 64 + lane]);
  }
  if (e < end) a += bf2f(XS[(size_t)esrc[e] * 64 + lane]);
  a += bf2f(XS[(size_t)wid * 64 + lane]);  // self: xs[n] (xs[n]*dn = x[n]*dn^2 after *dn)
  out[(size_t)wid * 64 + lane] = a * dn;
}

// ---------------- aggregate 128-ch bf16 (prescaled) + bias ----------------
__global__ __launch_bounds__(256) void aggregate128_bf16(const ushort* __restrict__ H,
                                                         const int* __restrict__ row_ptr,
                                                         const int* __restrict__ esrc,
                                                         const float* __restrict__ dis,
                                                         const float* __restrict__ bias,
                                                         float* __restrict__ out, int N) {
  int wid = (int)((blockIdx.x * 256 + threadIdx.x) >> 6);
  if (wid >= N) return;
  const int lane = threadIdx.x & 63;
  const float dn = dis[wid];
  const int beg = row_ptr[wid];
  const int end = row_ptr[wid + 1];
  float ax = 0.f, ay = 0.f;
  int e = beg;
  for (; e + 1 < end; e += 2) {
    int s0 = esrc[e], s1 = esrc[e + 1];
    uint u0 = *(const uint*)(H + (size_t)s0 * HID + 2 * lane);
    uint u1 = *(const uint*)(H + (size_t)s1 * HID + 2 * lane);
    ax += __uint_as_float(u0 << 16) + __uint_as_float(u1 << 16);
    ay += __uint_as_float(u0 & 0xFFFF0000u) + __uint_as_float(u1 & 0xFFFF0000u);
  }
  if (e < end) {
    uint u0 = *(const uint*)(H + (size_t)esrc[e] * HID + 2 * lane);
    ax += __uint_as_float(u0 << 16);
    ay += __uint_as_float(u0 & 0xFFFF0000u);
  }
  uint us = *(const uint*)(H + (size_t)wid * HID + 2 * lane);  // self
  ax += __uint_as_float(us << 16);
  ay += __uint_as_float(us & 0xFFFF0000u);
  float2 b = ((const float2*)bias)[lane];
  float2 r;
  r.x = ax * dn + b.x;
  r.y = ay * dn + b.y;
  ((float2*)(out + (size_t)wid * HID))[lane] = r;
}

// ---------------- GEMM tile: Y[N][128] = X[N][K] @ W[K][128] (+bias) ----------------
// 64 rows x 128 ch per block; thread = 4 rows x 8 contiguous ch.
// FUSE_NORM: instance-norm+relu applied to X during staging.
// OUT_BF16: output rounded to bf16; DIS_SCALE: multiply row by dis[row] first.
template <int K, bool FUSE_NORM, bool OUT_BF16, bool DIS_SCALE>
__global__ __launch_bounds__(256) void gemm_tile(const float* __restrict__ X,
                                                 const float* __restrict__ W,
                                                 const float* __restrict__ bias,
                                                 const int* __restrict__ batch,
                                                 const float* __restrict__ mean,
                                                 const float* __restrict__ inv,
                                                 const float* __restrict__ disv,
                                                 float* __restrict__ Yf,
                                                 ushort* __restrict__ Yh, int N) {
  __shared__ float Xs[64][68];
  __shared__ float Ws[64][HID];
  const int t = threadIdx.x;
  const int r0 = (t >> 4) * 4;
  const int c0 = (t & 15) * 8;
  const int row0 = blockIdx.x * 64;
  float acc[4][8] = {};
  for (int k0 = 0; k0 < K; k0 += 64) {
    for (int i = t; i < 64 * 32; i += 256) {
      int kk = i >> 5;
      int c4 = i & 31;
      ((float4*)&Ws[kk][0])[c4] = ((const float4*)(W + (size_t)(k0 + kk) * HID))[c4];
    }
    for (int i = t; i < 64 * 16; i += 256) {
      int r = i >> 4;
      int c4 = i & 15;
      int gr = row0 + r;
      float4 v = make_float4(0.f, 0.f, 0.f, 0.f);
      if (gr < N) {
        v = ((const float4*)(X + (size_t)gr * K + k0))[c4];
        if (FUSE_NORM) {
          int g = batch[gr];
          const float* mp = mean + g * HID + k0 + c4 * 4;
          const float* ip = inv + g * HID + k0 + c4 * 4;
          v.x = fmaxf((v.x - mp[0]) * ip[0], 0.f);
          v.y = fmaxf((v.y - mp[1]) * ip[1], 0.f);
          v.z = fmaxf((v.z - mp[2]) * ip[2], 0.f);
          v.w = fmaxf((v.w - mp[3]) * ip[3], 0.f);
        }
      }
      *(float4*)&Xs[r][c4 * 4] = v;
    }
    __syncthreads();
#pragma unroll 4
    for (int kk = 0; kk < 64; ++kk) {
      float4 w0 = *(const float4*)&Ws[kk][c0];
      float4 w1 = *(const float4*)&Ws[kk][c0 + 4];
      float xr[4];
#pragma unroll
      for (int i = 0; i < 4; ++i) xr[i] = Xs[r0 + i][kk];
#pragma unroll
      for (int i = 0; i < 4; ++i) {
        acc[i][0] += xr[i] * w0.x;
        acc[i][1] += xr[i] * w0.y;
        acc[i][2] += xr[i] * w0.z;
        acc[i][3] += xr[i] * w0.w;
        acc[i][4] += xr[i] * w1.x;
        acc[i][5] += xr[i] * w1.y;
        acc[i][6] += xr[i] * w1.z;
        acc[i][7] += xr[i] * w1.w;
      }
    }
    __syncthreads();
  }
  float bv[8];
#pragma unroll
  for (int j = 0; j < 8; ++j) bv[j] = bias ? bias[c0 + j] : 0.f;
#pragma unroll
  for (int i = 0; i < 4; ++i) {
    int gr = row0 + r0 + i;
    if (gr < N) {
      float ds = DIS_SCALE ? disv[gr] : 1.f;
      if (OUT_BF16) {
        uint4 u;
        u.x = (uint)f2bf((acc[i][0] + bv[0]) * ds) | ((uint)f2bf((acc[i][1] + bv[1]) * ds) << 16);
        u.y = (uint)f2bf((acc[i][2] + bv[2]) * ds) | ((uint)f2bf((acc[i][3] + bv[3]) * ds) << 16);
        u.z = (uint)f2bf((acc[i][4] + bv[4]) * ds) | ((uint)f2bf((acc[i][5] + bv[5]) * ds) << 16);
        u.w = (uint)f2bf((acc[i][6] + bv[6]) * ds) | ((uint)f2bf((acc[i][7] + bv[7]) * ds) << 16);
        *(uint4*)(Yh + (size_t)gr * HID + c0) = u;
      } else {
        float4 o0 = make_float4(acc[i][0] + bv[0], acc[i][1] + bv[1], acc[i][2] + bv[2],
                                acc[i][3] + bv[3]);
        float4 o1 = make_float4(acc[i][4] + bv[4], acc[i][5] + bv[5], acc[i][6] + bv[6],
                                acc[i][7] + bv[7]);
        *(float4*)(Yf + (size_t)gr * HID + c0) = o0;
        *(float4*)(Yf + (size_t)gr * HID + c0 + 4) = o1;
      }
    }
  }
}

// ---------------- per-graph sum/sumsq ----------------
__global__ __launch_bounds__(256) void stats_pass(const float* __restrict__ G,
                                                  const int* __restrict__ batch,
                                                  float* __restrict__ gsum,
                                                  float* __restrict__ gsq, int N) {
  const int c = threadIdx.x & 127;
  const int half = threadIdx.x >> 7;
  const int n0 = blockIdx.x * 64 + half * 32;
  const int n1 = min(n0 + 32, N);
  float s = 0.f, sq = 0.f;
  int cur = -1;
  for (int n = n0; n < n1; ++n) {
    int g = batch[n];
    if (g != cur) {
      if (cur >= 0) {
        atomicAdd(&gsum[cur * HID + c], s);
        atomicAdd(&gsq[cur * HID + c], sq);
      }
      cur = g;
      s = 0.f;
      sq = 0.f;
    }
    float val = G[(size_t)n * HID + c];
    s += val;
    sq += val * val;
  }
  if (cur >= 0) {
    atomicAdd(&gsum[cur * HID + c], s);
    atomicAdd(&gsq[cur * HID + c], sq);
  }
}

__global__ __launch_bounds__(256) void finalize_stats(const float* __restrict__ gsum,
                                                      const float* __restrict__ gsq,
                                                      const float* __restrict__ cnt,
                                                      float* __restrict__ mean,
                                                      float* __restrict__ inv) {
  int i = blockIdx.x * 256 + threadIdx.x;
  if (i >= NGRAPH * HID) return;
  int g = i >> 7;
  float c = fmaxf(cnt[g], 1.f);
  float m = gsum[i] / c;
  float v = gsq[i] / c - m * m;
  mean[i] = m;
  inv[i] = rsqrtf(v + EPSN);
}

__global__ __launch_bounds__(256) void norm_relu_pool(const float* __restrict__ G,
                                                      const int* __restrict__ batch,
                                                      const float* __restrict__ mean,
                                                      const float* __restrict__ inv,
                                                      float* __restrict__ pooled, int N) {
  const int c = threadIdx.x & 127;
  const int half = threadIdx.x >> 7;
  const int n0 = blockIdx.x * 64 + half * 32;
  const int n1 = min(n0 + 32, N);
  float s = 0.f;
  int cur = -1;
  for (int n = n0; n < n1; ++n) {
    int g = batch[n];
    if (g != cur) {
      if (cur >= 0) atomicAdd(&pooled[cur * HID + c], s);
      cur = g;
      s = 0.f;
    }
    float v = (G[(size_t)n * HID + c] - mean[g * HID + c]) * inv[g * HID + c];
    s += fmaxf(v, 0.f);
  }
  if (cur >= 0) atomicAdd(&pooled[cur * HID + c], s);
}

// ---------------- final head ----------------
__global__ __launch_bounds__(256) void final_head(const float* __restrict__ pooled_sum,
                                                  const float* __restrict__ cnt,
                                                  const float* __restrict__ gamma,
                                                  const float* __restrict__ beta,
                                                  const float* __restrict__ fcW,
                                                  const float* __restrict__ fcb,
                                                  float* __restrict__ out) {
  __shared__ float P[NGRAPH][HID];
  __shared__ float zs[HID], zb[HID];
  int t = threadIdx.x;
  for (int i = t; i < NGRAPH * HID; i += 256) {
    int g = i >> 7;
    P[g][i & 127] = pooled_sum[i] / fmaxf(cnt[g], 1.f);
  }
  __syncthreads();
  if (t < HID) {
    float m = 0.f;
    for (int g = 0; g < NGRAPH; ++g) m += P[g][t];
    m *= (1.f / NGRAPH);
    float v = 0.f;
    for (int g = 0; g < NGRAPH; ++g) {
      float d = P[g][t] - m;
      v += d * d;
    }
    v *= (1.f / NGRAPH);
    float sc = rsqrtf(v + EPSN) * gamma[t];
    zs[t] = sc;
    zb[t] = beta[t] - m * sc;
  }
  __syncthreads();
  if (t < NGRAPH * 2) {
    int g = t >> 1, k = t & 1;
    float acc = fcb[k];
    for (int c = 0; c < HID; ++c) {
      float z = P[g][c] * zs[c] + zb[c];
      acc += z * fcW[c * 2 + k];
    }
    out[t] = acc;
  }
}

extern "C" void kernel_launch(void* const* d_in, const int* in_sizes, int n_in,
                              void* d_out, int out_size, void* d_ws, size_t ws_size,
                              hipStream_t stream) {
  const float* x = (const float*)d_in[0];
  const int* ei = (const int*)d_in[1];     // int32
  const int* batch = (const int*)d_in[2];  // int32 (sorted)
  const float* W1 = (const float*)d_in[3];
  const float* b1 = (const float*)d_in[4];
  const float* W2 = (const float*)d_in[5];
  const float* b2 = (const float*)d_in[6];
  const float* gamma = (const float*)d_in[7];
  const float* beta = (const float*)d_in[8];
  const float* fcW = (const float*)d_in[9];
  const float* fcb = (const float*)d_in[10];
  float* out = (float*)d_out;

  const int N = in_sizes[2];
  const int E = in_sizes[1] / 2;
  const int* srcp = ei;
  const int* dstp = ei + E;
  const int NB = (N + 255) >> BSHIFT;  // buckets (<=512 for N<=131072)

  // workspace layout (floats)
  float* ws = (float*)d_ws;
  size_t off = 0;
  auto alloc = [&](size_t n) {
    float* p = ws + off;
    off += (n + 127) & ~(size_t)127;
    return p;
  };
  int* row_ptr = (int*)alloc(N + 1);
  int* esrc = (int*)alloc(E);
  float* recbuf = alloc((size_t)E * 2);  // int2 records; reused later as xs (bf16 Nx64)
  float* dis = alloc(N);
  float* y1 = alloc((size_t)N * 64);     // f32 Nx64; reused as h2s (bf16 Nx128)
  float* h1p = alloc((size_t)N * HID);   // f32: h1' then z
  int* bbase = (int*)alloc(NBMAX + 1);
  int* bcursor = (int*)alloc(NBMAX);
  int* gstart = (int*)alloc(NGRAPH + 1);
  float* zero0 = ws + off;               // zeroed region start
  int* bcnt = (int*)alloc(NBMAX);
  float* gsum1 = alloc(NGRAPH * HID);
  float* gsq1 = alloc(NGRAPH * HID);
  float* gsum2 = alloc(NGRAPH * HID);
  float* gsq2 = alloc(NGRAPH * HID);
  float* pooled = alloc(NGRAPH * HID);
  size_t zero_bytes = (size_t)((ws + off) - zero0) * sizeof(float);
  float* cnt = alloc(NGRAPH);
  float* mean1 = alloc(NGRAPH * HID);
  float* inv1 = alloc(NGRAPH * HID);
  float* mean2 = alloc(NGRAPH * HID);
  float* inv2 = alloc(NGRAPH * HID);

  int2* records = (int2*)recbuf;
  ushort* xs = (ushort*)recbuf;  // alias: records dead after build_csr
  ushort* h2s = (ushort*)y1;     // alias: y1 dead after gemm1

  const int nblkN = (N + 255) / 256;
  const int nblkE4k = (E + 4095) / 4096;

  hipMemsetAsync(zero0, 0, zero_bytes, stream);

  // graph segments + CSR build
  graph_starts<<<nblkN, 256, 0, stream>>>(batch, gstart, N);
  cnt_from_starts<<<1, 64, 0, stream>>>(gstart, cnt);
  bucket_count<<<nblkE4k, 256, 0, stream>>>(dstp, bcnt, E, NB);
  bucket_scan<<<1, 512, 0, stream>>>(bcnt, bbase, bcursor, NB, E);
  bin_edges<<<nblkE4k, 256, 0, stream>>>(srcp, dstp, bcursor, records, E, NB);
  build_csr<<<NB, 256, 0, stream>>>(records, bbase, row_ptr, dis, esrc, N, E);

  const int aggBlocks = (N + 3) / 4;     // one wave per node
  const int gemmBlocks = (N + 63) / 64;  // 64 rows per block

  // ---- layer 1: xs = bf16(x*dis); y1 = A-hat x ; h1' = y1 @ W1 + b1 ----
  xscale_bf16<<<(N * 16 + 255) / 256, 256, 0, stream>>>(x, dis, xs, N * 16);
  aggregate64_bf16<<<aggBlocks, 256, 0, stream>>>(xs, row_ptr, esrc, dis, y1, N);
  gemm_tile<64, false, false, false><<<gemmBlocks, 256, 0, stream>>>(
      y1, W1, b1, nullptr, nullptr, nullptr, nullptr, h1p, nullptr, N);
  stats_pass<<<(N + 63) / 64, 256, 0, stream>>>(h1p, batch, gsum1, gsq1, N);
  finalize_stats<<<(NGRAPH * HID + 255) / 256, 256, 0, stream>>>(gsum1, gsq1, cnt, mean1, inv1);

  // ---- layer 2: h2s = bf16(relu(norm(h1')) @ W2 * dis) ; z = A-hat h2 + b2 ----
  gemm_tile<128, true, true, true><<<gemmBlocks, 256, 0, stream>>>(
      h1p, W2, nullptr, batch, mean1, inv1, dis, nullptr, h2s, N);
  aggregate128_bf16<<<aggBlocks, 256, 0, stream>>>(h2s, row_ptr, esrc, dis, b2, h1p, N);
  stats_pass<<<(N + 63) / 64, 256, 0, stream>>>(h1p, batch, gsum2, gsq2, N);
  finalize_stats<<<(NGRAPH * HID + 255) / 256, 256, 0, stream>>>(gsum2, gsq2, cnt, mean2, inv2);
  norm_relu_pool<<<(N + 63) / 64, 256, 0, stream>>>(h1p, batch, mean2, inv2, pooled, N);

  // ---- head ----
  final_head<<<1, 256, 0, stream>>>(pooled, cnt, gamma, beta, fcW, fcb, out);
}